// Round 2
// baseline (272.912 us; speedup 1.0000x reference)
//
#include <hip/hip_runtime.h>
#include <hip/hip_bf16.h>
#include <cstdint>

#define B_ 4
#define T_ 2048
#define C_ 1024
#define H_ 16
#define D_ 64
#define M_ (B_*T_)   // 8192
#define N3 (3*C_)    // 3072

typedef __bf16 bf16;
typedef __bf16 bf16x8 __attribute__((ext_vector_type(8)));
typedef __bf16 bf16x4 __attribute__((ext_vector_type(4)));
typedef float  floatx4 __attribute__((ext_vector_type(4)));

// async global->LDS, 16B per lane; LDS dest = wave-uniform base + lane*16
__device__ __forceinline__ void gl_lds16(const bf16* g, bf16* l) {
  __builtin_amdgcn_global_load_lds(
      (__attribute__((address_space(1))) void*)(void*)g,
      (__attribute__((address_space(3))) void*)(void*)l,
      16, 0, 0);
}

// truncating fp32->bf16 pair pack (P matrix only; rel err <= 2^-8)
__device__ __forceinline__ uint32_t pack_bf16_trunc(float lo, float hi) {
  union { float f; uint32_t u; } a, b;
  a.f = lo; b.f = hi;
  return (a.u >> 16) | (b.u & 0xffff0000u);
}

// ---------------- cast fp32 -> bf16 ----------------
__global__ void cast_to_bf16(const float* __restrict__ in, bf16* __restrict__ out, int n) {
  int i = (blockIdx.x * blockDim.x + threadIdx.x) * 4;
  if (i < n) {
    const float4 f = *(const float4*)(in + i);
    bf16x4 o;
    o.x = (bf16)f.x; o.y = (bf16)f.y; o.z = (bf16)f.z; o.w = (bf16)f.w;
    *(bf16x4*)(out + i) = o;
  }
}

// ---------------- transpose + cast: in [R][C] fp32 -> out [C][R] bf16 ----------------
__global__ void transpose_cast(const float* __restrict__ in, bf16* __restrict__ out,
                               int R, int C) {
  __shared__ float tile[32][33];
  int r0 = blockIdx.y * 32, c0 = blockIdx.x * 32;
  int tx = threadIdx.x & 31, ty = threadIdx.x >> 5;  // 32x8
  #pragma unroll
  for (int j = 0; j < 32; j += 8)
    tile[ty + j][tx] = in[(size_t)(r0 + ty + j) * C + c0 + tx];
  __syncthreads();
  #pragma unroll
  for (int j = 0; j < 32; j += 8)
    out[(size_t)(c0 + ty + j) * R + r0 + tx] = (bf16)tile[tx][ty + j];
}

// ---------------- V [B,H,T,D] -> Vtp [B,H,D,T] with per-64 key permutation ----------
__global__ __launch_bounds__(256)
void transpose_v(const bf16* __restrict__ in, bf16* __restrict__ out) {
  __shared__ __attribute__((aligned(16))) bf16 tileN[64 * 64];
  const int tid = threadIdx.x;
  const int bh = blockIdx.z;
  const int t0 = blockIdx.x * 64;
  const int sk = tid >> 2, scc = tid & 3;
  {
    const bf16* p = in + ((size_t)bh * T_ + t0 + sk) * D_ + scc * 16;
    const bf16x8 r0 = *(const bf16x8*)p;
    const bf16x8 r1 = *(const bf16x8*)(p + 8);
    *(bf16x8*)(tileN + sk * 64 + ((2 * scc)     ^ (sk & 7)) * 8) = r0;
    *(bf16x8*)(tileN + sk * 64 + ((2 * scc + 1) ^ (sk & 7)) * 8) = r1;
  }
  __syncthreads();
  const int tc = (tid & 7) * 8;   // slot base
  #pragma unroll
  for (int half = 0; half < 2; half++) {
    const int d = (tid >> 3) + half * 32;
    bf16x8 o;
    #pragma unroll
    for (int j = 0; j < 8; j++) {
      const int slot = tc + j;
      const int row = 16 * (slot & 3) + (slot >> 2);  // key for this slot
      o[j] = tileN[row * 64 + (((d >> 3) ^ (row & 7)) * 8) + (d & 7)];
    }
    *(bf16x8*)(out + ((size_t)bh * D_ + d) * T_ + t0 + tc) = o;
  }
}

// ---------------- legacy 128x128 GEMM (kept for the proj GEMM, N=1024) ----------------
template<int MODE>
__global__ __launch_bounds__(256)
void gemm_bt(const bf16* __restrict__ A, const bf16* __restrict__ Bt,
             const float* __restrict__ bias, float* __restrict__ out,
             bf16* __restrict__ qo, bf16* __restrict__ ko, bf16* __restrict__ vo,
             int M, int N, int K)
{
  __shared__ __attribute__((aligned(16))) bf16 As[128 * 32];
  __shared__ __attribute__((aligned(16))) bf16 Bs[128 * 32];

  const int tid  = threadIdx.x;
  const int w    = tid >> 6;
  const int lane = tid & 63;
  const int quad = lane >> 4;
  const int l16  = lane & 15;
  const int wm   = w & 1, wn = w >> 1;
  const int m0   = blockIdx.y * 128, n0 = blockIdx.x * 128;

  floatx4 acc[4][4] = {};

  const int lrow = lane >> 2;
  const int lk   = (lane & 3) * 8;

  const bf16* aptr = A  + (size_t)(m0 + w * 32 + lrow) * K + lk;
  const bf16* bptr = Bt + (size_t)(n0 + w * 32 + lrow) * K + lk;
  bf16* asl = As + w * 1024;
  bf16* bsl = Bs + w * 1024;

  for (int k0 = 0; k0 < K; k0 += 32) {
    gl_lds16(aptr,          asl);
    gl_lds16(aptr + 16 * K, asl + 512);
    gl_lds16(bptr,          bsl);
    gl_lds16(bptr + 16 * K, bsl + 512);
    aptr += 32; bptr += 32;
    __syncthreads();

    bf16x8 af[4], bfb[4];
    #pragma unroll
    for (int i = 0; i < 4; i++)
      af[i] = *(const bf16x8*)(As + (wm * 64 + i * 16 + l16) * 32 + quad * 8);
    #pragma unroll
    for (int i = 0; i < 4; i++)
      bfb[i] = *(const bf16x8*)(Bs + (wn * 64 + i * 16 + l16) * 32 + quad * 8);
    #pragma unroll
    for (int mi = 0; mi < 4; mi++)
      #pragma unroll
      for (int ni = 0; ni < 4; ni++)
        acc[mi][ni] = __builtin_amdgcn_mfma_f32_16x16x32_bf16(af[mi], bfb[ni], acc[mi][ni], 0, 0, 0);
    __syncthreads();
  }

  #pragma unroll
  for (int mi = 0; mi < 4; mi++) {
    #pragma unroll
    for (int ni = 0; ni < 4; ni++) {
      const int col = n0 + wn * 64 + ni * 16 + l16;
      const float bv = bias[col];
      #pragma unroll
      for (int r = 0; r < 4; r++) {
        const int row = m0 + wm * 64 + mi * 16 + quad * 4 + r;
        const float val = acc[mi][ni][r] + bv;
        if (MODE == 0) {
          const int b = row >> 11, t = row & 2047;
          const int s = col >> 10, c = col & 1023;
          const int h = c >> 6,  d = c & 63;
          bf16* dst = (s == 0) ? qo : (s == 1) ? ko : vo;
          dst[((size_t)(b * H_ + h) * T_ + t) * D_ + d] = (bf16)val;
        } else {
          out[(size_t)row * N + col] = val;
        }
      }
    }
  }
}

// ================= 256x256 8-phase GEMM (T2 swizzle + T3/T4 counted vmcnt + T5) =======
// BM=BN=256, BK=64, 512 threads = 8 waves (2M x 4N), per-wave C = 128x64 (8x4 frags).
// LDS 128 KiB: A/B tiles 256x64 bf16, double-buffered. Stage unit = "half" (128 rows,
// 16 KiB, 2 global_load_lds_dwordx4 per thread). 4 phases per K-tile, one C-quadrant
// (4Mx2N frags, 16 MFMA over K=64) + one half staged per phase. Raw s_barrier only
// (no vmcnt(0) drain); s_waitcnt vmcnt(4) once per K-tile.
//
// Swizzle (T2, rule 21 both-sides): LDS row = 8 slots x 16B. Physical slot holds
// logical slot ^ (row&7): stage keeps LDS write linear and pre-swizzles the per-lane
// GLOBAL source slot ((l&7)^(l>>3)); ds_read applies slot^(row&7). 16-way conflict -> 2-way (free).
//
// Stage schedule (hazard-checked: a region is staged >=1 full phase after its last read;
// readers protected by the per-K-tile vmcnt(4)+s_barrier):
//   ph(0,0): stage (t+1).A1   ph(0,1): stage (t+1).B1
//   ph(1,0): stage (t+2).A0   ph(1,1): stage (t+2).B0, then vmcnt(4)
// At the tile boundary the 4 newest loads are (t+2).{A0,B0} -> vmcnt(4) proves
// (t+1) fully resident. Prologue: t0.{A0,A1,B0,B1}, t1.{A0,B0}, vmcnt(4).

__device__ __forceinline__ void stage8(const bf16* g, int K, bf16* lds, int lane) {
  const int r = lane >> 3, s = (lane & 7) ^ r;   // inverse-swizzled global slot
  gl_lds16(g + (size_t)r * K + s * 8, lds);      // lds arg wave-uniform; HW adds lane*16B
}
__device__ __forceinline__ void stage_half(const bf16* g, int K, bf16* lds, int wv, int lane) {
  stage8(g + (size_t)(wv * 16) * K,     K, lds + (wv * 16) * 64, lane);
  stage8(g + (size_t)(wv * 16 + 8) * K, K, lds + (wv * 16 + 8) * 64, lane);
}

#define GBAR asm volatile("s_barrier" ::: "memory")

template<int MODE>
__global__ __launch_bounds__(512, 2)
void gemm256(const bf16* __restrict__ A, const bf16* __restrict__ Bt,
             const float* __restrict__ bias, float* __restrict__ out,
             bf16* __restrict__ qo, bf16* __restrict__ ko, bf16* __restrict__ vo,
             int M, int N, int K)
{
  __shared__ __attribute__((aligned(16))) bf16 As[2][256 * 64];
  __shared__ __attribute__((aligned(16))) bf16 Bs[2][256 * 64];

  const int tid  = threadIdx.x;
  const int wv   = tid >> 6, lane = tid & 63;
  const int quad = lane >> 4, l16 = lane & 15;
  const int wm   = wv >> 2, wn = wv & 3;          // 2 x 4 wave grid
  const int n0   = blockIdx.x * 256, m0 = blockIdx.y * 256;
  const int NTT  = K >> 6;

  floatx4 acc[8][4] = {};

  const bf16* Abase = A  + (size_t)m0 * K;
  const bf16* Bbase = Bt + (size_t)n0 * K;

  // prologue: t0 all 4 halves, t1 {A0,B0}
  stage_half(Abase,                  K, As[0],            wv, lane);
  stage_half(Abase + (size_t)128*K,  K, As[0] + 128 * 64, wv, lane);
  stage_half(Bbase,                  K, Bs[0],            wv, lane);
  stage_half(Bbase + (size_t)128*K,  K, Bs[0] + 128 * 64, wv, lane);
  stage_half(Abase + 64,             K, As[1],            wv, lane);
  stage_half(Bbase + 64,             K, Bs[1],            wv, lane);
  asm volatile("s_waitcnt vmcnt(4)" ::: "memory");
  GBAR;

#define LOADA(qm)                                                          \
  _Pragma("unroll")                                                        \
  for (int mi = 0; mi < 4; mi++) {                                         \
    const int row = wm * 128 + (qm) * 64 + mi * 16 + l16;                  \
    const bf16* rp = bufA + row * 64;                                      \
    af[mi][0] = *(const bf16x8*)(rp + (( quad      ^ (row & 7)) * 8));     \
    af[mi][1] = *(const bf16x8*)(rp + (((4 | quad) ^ (row & 7)) * 8));     \
  }
#define LOADB(qn)                                                          \
  _Pragma("unroll")                                                        \
  for (int ni = 0; ni < 2; ni++) {                                         \
    const int row = wn * 64 + (qn) * 32 + ni * 16 + l16;                   \
    const bf16* rp = bufB + row * 64;                                      \
    bfr[ni][0] = *(const bf16x8*)(rp + (( quad      ^ (row & 7)) * 8));    \
    bfr[ni][1] = *(const bf16x8*)(rp + (((4 | quad) ^ (row & 7)) * 8));    \
  }
#define MM(qm, qn)                                                         \
  __builtin_amdgcn_s_setprio(1);                                           \
  _Pragma("unroll")                                                        \
  for (int mi = 0; mi < 4; mi++)                                           \
    _Pragma("unroll")                                                      \
    for (int ni = 0; ni < 2; ni++) {                                       \
      acc[(qm)*4+mi][(qn)*2+ni] = __builtin_amdgcn_mfma_f32_16x16x32_bf16( \
          af[mi][0], bfr[ni][0], acc[(qm)*4+mi][(qn)*2+ni], 0, 0, 0);      \
      acc[(qm)*4+mi][(qn)*2+ni] = __builtin_amdgcn_mfma_f32_16x16x32_bf16( \
          af[mi][1], bfr[ni][1], acc[(qm)*4+mi][(qn)*2+ni], 0, 0, 0);      \
    }                                                                      \
  __builtin_amdgcn_s_setprio(0);

  #pragma unroll 1
  for (int t = 0; t < NTT; t++) {
    const int cur = t & 1;
    const bf16* bufA = As[cur];
    const bf16* bufB = Bs[cur];
    bf16* nA = As[cur ^ 1];   // tile t+1 buffer
    bf16* nB = Bs[cur ^ 1];
    bf16* cA = As[cur];       // tile t+2 buffer (this one, being freed)
    bf16* cB = Bs[cur];
    const int kn1 = (t + 1) * 64, kn2 = (t + 2) * 64;
    const bool h1 = (t + 1 < NTT), h2 = (t + 2 < NTT);

    bf16x8 af[4][2], bfr[2][2];

    // ---- phase (0,0): read A-half0 frags + B-half0 frags; stage (t+1).A1 ----
    LOADA(0);
    LOADB(0);
    if (h1) stage_half(Abase + (size_t)128 * K + kn1, K, nA + 128 * 64, wv, lane);
    GBAR;
    MM(0, 0);
    GBAR;

    // ---- phase (0,1): read B-half1 frags (A reused); stage (t+1).B1 ----
    LOADB(1);
    if (h1) stage_half(Bbase + (size_t)128 * K + kn1, K, nB + 128 * 64, wv, lane);
    GBAR;
    MM(0, 1);
    GBAR;

    // ---- phase (1,0): read A-half1 + B-half0 frags; stage (t+2).A0 ----
    LOADA(1);
    LOADB(0);
    if (h2) stage_half(Abase + kn2, K, cA, wv, lane);
    GBAR;
    MM(1, 0);
    GBAR;

    // ---- phase (1,1): read B-half1 frags; stage (t+2).B0; counted vmcnt ----
    LOADB(1);
    if (h2) stage_half(Bbase + kn2, K, cB, wv, lane);
    GBAR;
    MM(1, 1);
    asm volatile("s_waitcnt vmcnt(4)" ::: "memory");
    GBAR;
  }

#undef LOADA
#undef LOADB
#undef MM

  // epilogue
  #pragma unroll
  for (int mi8 = 0; mi8 < 8; mi8++) {
    #pragma unroll
    for (int nf = 0; nf < 4; nf++) {
      const int col = n0 + wn * 64 + nf * 16 + l16;
      const float bv = bias[col];
      #pragma unroll
      for (int r = 0; r < 4; r++) {
        const int row = m0 + wm * 128 + mi8 * 16 + quad * 4 + r;
        const float val = acc[mi8][nf][r] + bv;
        if (MODE == 0) {
          const int b = row >> 11, tt = row & 2047;
          const int s = col >> 10, c = col & 1023;
          const int h = c >> 6, d = c & 63;
          bf16* dst = (s == 0) ? qo : (s == 1) ? ko : vo;
          dst[((size_t)(b * H_ + h) * T_ + tt) * D_ + d] = (bf16)val;
        } else {
          out[(size_t)row * N + col] = val;
        }
      }
    }
  }
}

// ---------------- flash attention (unchanged this round) ----------------
__global__ __launch_bounds__(256)
void attn_kernel(const bf16* __restrict__ Q, const bf16* __restrict__ Kp,
                 const bf16* __restrict__ Vtp, bf16* __restrict__ Y)
{
  __shared__ __attribute__((aligned(16))) bf16 Ks[2][64 * 72];  // [key][d]
  __shared__ __attribute__((aligned(16))) bf16 Vs[2][64 * 72];  // [d][slot]
  __shared__ __attribute__((aligned(16))) bf16 Ps[4][16 * 72];  // per-wave [row][slot]

  const int tid  = threadIdx.x;
  const int w    = tid >> 6, lane = tid & 63;
  const int quad = lane >> 4, l16 = lane & 15;
  const int bh = blockIdx.x;
  const int b = bh >> 4, h = bh & 15;
  const int pr = blockIdx.y;        // pair index 0..7

  const int sk = tid >> 2;          // staging row (key for K, d for V)
  const int sc = (tid & 3) * 16;    // staging 32B segment

  const float SC = 0.125f * 1.44269504088896f;  // 1/sqrt(D) * log2(e)

  #pragma unroll 1
  for (int sel = 0; sel < 2; sel++) {
    const int qt = sel ? pr : 15 - pr;   // heavy tile first
    const int q0 = qt * 128;
    const int nch = 2 * qt + 2;

    bf16x8 qf[2][2];
    #pragma unroll
    for (int mt = 0; mt < 2; mt++) {
      const bf16* qp = Q + ((size_t)bh * T_ + q0 + mt * 64 + w * 16 + l16) * D_ + quad * 8;
      qf[mt][0] = *(const bf16x8*)qp;
      qf[mt][1] = *(const bf16x8*)(qp + 32);
    }

    floatx4 o[2][4] = {};
    float l_r[2][4] = {};

    const bf16* kpp = Kp  + (size_t)bh * T_ * D_ + (size_t)sk * D_ + sc;
    const bf16* vpp = Vtp + (size_t)bh * D_ * T_ + (size_t)sk * T_ + sc;

    {
      const bf16x8 k0 = *(const bf16x8*)kpp, k1 = *(const bf16x8*)(kpp + 8);
      const bf16x8 v0 = *(const bf16x8*)vpp, v1 = *(const bf16x8*)(vpp + 8);
      bf16* kd = Ks[0] + sk * 72 + sc;
      *(bf16x8*)kd = k0; *(bf16x8*)(kd + 8) = k1;
      bf16* vd = Vs[0] + sk * 72 + sc;
      *(bf16x8*)vd = v0; *(bf16x8*)(vd + 8) = v1;
      kpp += 64 * D_; vpp += 64;
    }
    __syncthreads();

    #pragma unroll 1
    for (int c = 0; c < nch; c++) {
      const int cur = c & 1;

      bf16x8 nk0, nk1, nv0, nv1;
      const bool have = (c + 1 < nch);
      if (have) {
        nk0 = *(const bf16x8*)kpp; nk1 = *(const bf16x8*)(kpp + 8);
        nv0 = *(const bf16x8*)vpp; nv1 = *(const bf16x8*)(vpp + 8);
        kpp += 64 * D_; vpp += 64;
      }

      const bf16* KsC = Ks[cur];
      const bf16* VsC = Vs[cur];
      const int kv0 = c * 64;
      const bool act0 = (c < nch - 1);  // mt0 fully masked on last chunk

      floatx4 s[2][4];
      #pragma unroll
      for (int nt = 0; nt < 4; nt++) {
        const bf16x8 kf0 = *(const bf16x8*)(KsC + (nt * 16 + l16) * 72 + quad * 8);
        const bf16x8 kf1 = *(const bf16x8*)(KsC + (nt * 16 + l16) * 72 + 32 + quad * 8);
        if (act0) {
          floatx4 z = {};
          z = __builtin_amdgcn_mfma_f32_16x16x32_bf16(qf[0][0], kf0, z, 0, 0, 0);
          s[0][nt] = __builtin_amdgcn_mfma_f32_16x16x32_bf16(qf[0][1], kf1, z, 0, 0, 0);
        }
        floatx4 z = {};
        z = __builtin_amdgcn_mfma_f32_16x16x32_bf16(qf[1][0], kf0, z, 0, 0, 0);
        s[1][nt] = __builtin_amdgcn_mfma_f32_16x16x32_bf16(qf[1][1], kf1, z, 0, 0, 0);
      }

      bf16x8 vfr[4][2];
      #pragma unroll
      for (int nt = 0; nt < 4; nt++) {
        vfr[nt][0] = *(const bf16x8*)(VsC + (nt * 16 + l16) * 72 + quad * 8);
        vfr[nt][1] = *(const bf16x8*)(VsC + (nt * 16 + l16) * 72 + 32 + quad * 8);
      }

      #pragma unroll
      for (int mt = 0; mt < 2; mt++) {
        if (mt == 0 && !act0) continue;
        const bool diag = (c == 2 * qt + mt);
        #pragma unroll
        for (int r = 0; r < 4; r++) {
          const int qrow = q0 + mt * 64 + w * 16 + quad * 4 + r;
          float x0 = s[mt][0][r], x1 = s[mt][1][r], x2 = s[mt][2][r], x3 = s[mt][3][r];
          if (diag) {
            if (kv0      + l16 > qrow) x0 = -1e30f;
            if (kv0 + 16 + l16 > qrow) x1 = -1e30f;
            if (kv0 + 32 + l16 > qrow) x2 = -1e30f;
            if (kv0 + 48 + l16 > qrow) x3 = -1e30f;
          }
          const float e0 = __builtin_amdgcn_exp2f(fmaf(x0, SC, -8.f));
          const float e1 = __builtin_amdgcn_exp2f(fmaf(x1, SC, -8.f));
          const float e2 = __builtin_amdgcn_exp2f(fmaf(x2, SC, -8.f));
          const float e3 = __builtin_amdgcn_exp2f(fmaf(x3, SC, -8.f));
          l_r[mt][r] += (e0 + e1) + (e2 + e3);
          uint2 pk;
          pk.x = pack_bf16_trunc(e0, e1);
          pk.y = pack_bf16_trunc(e2, e3);
          *(uint2*)(&Ps[w][(quad * 4 + r) * 72 + l16 * 4]) = pk;
        }
        const bf16x8 pf0 = *(const bf16x8*)(&Ps[w][l16 * 72 + quad * 8]);
        const bf16x8 pf1 = *(const bf16x8*)(&Ps[w][l16 * 72 + 32 + quad * 8]);
        #pragma unroll
        for (int nt = 0; nt < 4; nt++) {
          o[mt][nt] = __builtin_amdgcn_mfma_f32_16x16x32_bf16(pf0, vfr[nt][0], o[mt][nt], 0, 0, 0);
          o[mt][nt] = __builtin_amdgcn_mfma_f32_16x16x32_bf16(pf1, vfr[nt][1], o[mt][nt], 0, 0, 0);
        }
      }

      if (have) {
        bf16* kd = Ks[cur ^ 1] + sk * 72 + sc;
        *(bf16x8*)kd = nk0; *(bf16x8*)(kd + 8) = nk1;
        bf16* vd = Vs[cur ^ 1] + sk * 72 + sc;
        *(bf16x8*)vd = nv0; *(bf16x8*)(vd + 8) = nv1;
      }
      __syncthreads();
    }

    #pragma unroll
    for (int mt = 0; mt < 2; mt++) {
      #pragma unroll
      for (int r = 0; r < 4; r++) {
        float ls = l_r[mt][r];
        ls += __shfl_xor(ls, 1);
        ls += __shfl_xor(ls, 2);
        ls += __shfl_xor(ls, 4);
        ls += __shfl_xor(ls, 8);
        const float inv = 1.f / ls;
        const int t = q0 + mt * 64 + w * 16 + quad * 4 + r;
        #pragma unroll
        for (int nt = 0; nt < 4; nt++)
          Y[((size_t)b * T_ + t) * C_ + h * D_ + nt * 16 + l16] = (bf16)(o[mt][nt][r] * inv);
      }
    }
  }
}

extern "C" void kernel_launch(void* const* d_in, const int* in_sizes, int n_in,
                              void* d_out, int out_size, void* d_ws, size_t ws_size,
                              hipStream_t stream)
{
  const float* x      = (const float*)d_in[0];
  const float* W_attn = (const float*)d_in[1];
  const float* b_attn = (const float*)d_in[2];
  const float* W_proj = (const float*)d_in[3];
  const float* b_proj = (const float*)d_in[4];
  float* out = (float*)d_out;

  bf16* xb  = (bf16*)d_ws;                  // [8192,1024]; reused as Vtp after gemm<0>
  bf16* wat = xb  + (size_t)M_ * C_;
  bf16* wpt = wat + (size_t)N3 * C_;
  bf16* qb  = wpt + (size_t)C_ * C_;
  bf16* kb  = qb  + (size_t)M_ * C_;
  bf16* vb  = kb  + (size_t)M_ * C_;
  bf16* yb  = vb  + (size_t)M_ * C_;
  bf16* vtb = xb;                           // [B,H,D,T] permuted

  cast_to_bf16<<<dim3(M_ * C_ / 1024), 256, 0, stream>>>(x, xb, M_ * C_);
  transpose_cast<<<dim3(N3 / 32, C_ / 32), 256, 0, stream>>>(W_attn, wat, C_, N3);
  transpose_cast<<<dim3(C_ / 32, C_ / 32), 256, 0, stream>>>(W_proj, wpt, C_, C_);
  gemm256<0><<<dim3(N3 / 256, M_ / 256), 512, 0, stream>>>(
      xb, wat, b_attn, nullptr, qb, kb, vb, M_, N3, C_);
  transpose_v<<<dim3(T_ / 64, 1, B_ * H_), 256, 0, stream>>>(vb, vtb);
  attn_kernel<<<dim3(B_ * H_, 8), 256, 0, stream>>>(qb, kb, vtb, yb);
  gemm_bt<1><<<dim3(C_ / 128, M_ / 128), 256, 0, stream>>>(
      yb, wpt, b_proj, out, nullptr, nullptr, nullptr, M_, C_, C_);
}

// Round 3
// 270.028 us; speedup vs baseline: 1.0107x; 1.0107x over previous
//
#include <hip/hip_runtime.h>
#include <hip/hip_bf16.h>
#include <cstdint>

#define B_ 4
#define T_ 2048
#define C_ 1024
#define H_ 16
#define D_ 64
#define M_ (B_*T_)   // 8192
#define N3 (3*C_)    // 3072

typedef __bf16 bf16;
typedef __bf16 bf16x8 __attribute__((ext_vector_type(8)));
typedef __bf16 bf16x4 __attribute__((ext_vector_type(4)));
typedef float  floatx4 __attribute__((ext_vector_type(4)));

// async global->LDS, 16B per lane; LDS dest = wave-uniform base + lane*16
__device__ __forceinline__ void gl_lds16(const bf16* g, bf16* l) {
  __builtin_amdgcn_global_load_lds(
      (__attribute__((address_space(1))) void*)(void*)g,
      (__attribute__((address_space(3))) void*)(void*)l,
      16, 0, 0);
}

// truncating fp32->bf16 pair pack (P matrix only; rel err <= 2^-8)
__device__ __forceinline__ uint32_t pack_bf16_trunc(float lo, float hi) {
  union { float f; uint32_t u; } a, b;
  a.f = lo; b.f = hi;
  return (a.u >> 16) | (b.u & 0xffff0000u);
}

// ---------------- cast fp32 -> bf16 ----------------
__global__ void cast_to_bf16(const float* __restrict__ in, bf16* __restrict__ out, int n) {
  int i = (blockIdx.x * blockDim.x + threadIdx.x) * 4;
  if (i < n) {
    const float4 f = *(const float4*)(in + i);
    bf16x4 o;
    o.x = (bf16)f.x; o.y = (bf16)f.y; o.z = (bf16)f.z; o.w = (bf16)f.w;
    *(bf16x4*)(out + i) = o;
  }
}

// ---------------- transpose + cast: in [R][C] fp32 -> out [C][R] bf16 ----------------
__global__ void transpose_cast(const float* __restrict__ in, bf16* __restrict__ out,
                               int R, int C) {
  __shared__ float tile[32][33];
  int r0 = blockIdx.y * 32, c0 = blockIdx.x * 32;
  int tx = threadIdx.x & 31, ty = threadIdx.x >> 5;  // 32x8
  #pragma unroll
  for (int j = 0; j < 32; j += 8)
    tile[ty + j][tx] = in[(size_t)(r0 + ty + j) * C + c0 + tx];
  __syncthreads();
  #pragma unroll
  for (int j = 0; j < 32; j += 8)
    out[(size_t)(c0 + ty + j) * R + r0 + tx] = (bf16)tile[tx][ty + j];
}

// ---------------- V [B,H,T,D] -> Vtp [B,H,D,T] with per-64 key permutation ----------
__global__ __launch_bounds__(256)
void transpose_v(const bf16* __restrict__ in, bf16* __restrict__ out) {
  __shared__ __attribute__((aligned(16))) bf16 tileN[64 * 64];
  const int tid = threadIdx.x;
  const int bh = blockIdx.z;
  const int t0 = blockIdx.x * 64;
  const int sk = tid >> 2, scc = tid & 3;
  {
    const bf16* p = in + ((size_t)bh * T_ + t0 + sk) * D_ + scc * 16;
    const bf16x8 r0 = *(const bf16x8*)p;
    const bf16x8 r1 = *(const bf16x8*)(p + 8);
    *(bf16x8*)(tileN + sk * 64 + ((2 * scc)     ^ (sk & 7)) * 8) = r0;
    *(bf16x8*)(tileN + sk * 64 + ((2 * scc + 1) ^ (sk & 7)) * 8) = r1;
  }
  __syncthreads();
  const int tc = (tid & 7) * 8;   // slot base
  #pragma unroll
  for (int half = 0; half < 2; half++) {
    const int d = (tid >> 3) + half * 32;
    bf16x8 o;
    #pragma unroll
    for (int j = 0; j < 8; j++) {
      const int slot = tc + j;
      const int row = 16 * (slot & 3) + (slot >> 2);  // key for this slot
      o[j] = tileN[row * 64 + (((d >> 3) ^ (row & 7)) * 8) + (d & 7)];
    }
    *(bf16x8*)(out + ((size_t)bh * D_ + d) * T_ + t0 + tc) = o;
  }
}

// ---------------- legacy 128x128 GEMM (kept for the proj GEMM, N=1024) ----------------
template<int MODE>
__global__ __launch_bounds__(256)
void gemm_bt(const bf16* __restrict__ A, const bf16* __restrict__ Bt,
             const float* __restrict__ bias, float* __restrict__ out,
             bf16* __restrict__ qo, bf16* __restrict__ ko, bf16* __restrict__ vo,
             int M, int N, int K)
{
  __shared__ __attribute__((aligned(16))) bf16 As[128 * 32];
  __shared__ __attribute__((aligned(16))) bf16 Bs[128 * 32];

  const int tid  = threadIdx.x;
  const int w    = tid >> 6;
  const int lane = tid & 63;
  const int quad = lane >> 4;
  const int l16  = lane & 15;
  const int wm   = w & 1, wn = w >> 1;
  const int m0   = blockIdx.y * 128, n0 = blockIdx.x * 128;

  floatx4 acc[4][4] = {};

  const int lrow = lane >> 2;
  const int lk   = (lane & 3) * 8;

  const bf16* aptr = A  + (size_t)(m0 + w * 32 + lrow) * K + lk;
  const bf16* bptr = Bt + (size_t)(n0 + w * 32 + lrow) * K + lk;
  bf16* asl = As + w * 1024;
  bf16* bsl = Bs + w * 1024;

  for (int k0 = 0; k0 < K; k0 += 32) {
    gl_lds16(aptr,          asl);
    gl_lds16(aptr + 16 * K, asl + 512);
    gl_lds16(bptr,          bsl);
    gl_lds16(bptr + 16 * K, bsl + 512);
    aptr += 32; bptr += 32;
    __syncthreads();

    bf16x8 af[4], bfb[4];
    #pragma unroll
    for (int i = 0; i < 4; i++)
      af[i] = *(const bf16x8*)(As + (wm * 64 + i * 16 + l16) * 32 + quad * 8);
    #pragma unroll
    for (int i = 0; i < 4; i++)
      bfb[i] = *(const bf16x8*)(Bs + (wn * 64 + i * 16 + l16) * 32 + quad * 8);
    #pragma unroll
    for (int mi = 0; mi < 4; mi++)
      #pragma unroll
      for (int ni = 0; ni < 4; ni++)
        acc[mi][ni] = __builtin_amdgcn_mfma_f32_16x16x32_bf16(af[mi], bfb[ni], acc[mi][ni], 0, 0, 0);
    __syncthreads();
  }

  #pragma unroll
  for (int mi = 0; mi < 4; mi++) {
    #pragma unroll
    for (int ni = 0; ni < 4; ni++) {
      const int col = n0 + wn * 64 + ni * 16 + l16;
      const float bv = bias[col];
      #pragma unroll
      for (int r = 0; r < 4; r++) {
        const int row = m0 + wm * 64 + mi * 16 + quad * 4 + r;
        const float val = acc[mi][ni][r] + bv;
        if (MODE == 0) {
          const int b = row >> 11, t = row & 2047;
          const int s = col >> 10, c = col & 1023;
          const int h = c >> 6,  d = c & 63;
          bf16* dst = (s == 0) ? qo : (s == 1) ? ko : vo;
          dst[((size_t)(b * H_ + h) * T_ + t) * D_ + d] = (bf16)val;
        } else {
          out[(size_t)row * N + col] = val;
        }
      }
    }
  }
}

// ================= 256x256 8-phase GEMM (T2 swizzle + T3/T4 counted vmcnt + T5) =======
// BM=BN=256, BK=64, 512 threads = 8 waves (2M x 4N), per-wave C = 128x64 (8x4 frags).
// LDS 128 KiB double-buffered. 4 phases per K-tile; 24 b128 reads/wave/K-tile (the
// minimum: all 4 B-frag pairs held in registers across phases, no re-reads).
//
// Stage schedule (race-free: every cur-buffer write is in a phase strictly after the
// barrier closing that region's last reader; A regions read ph00/ph10, B ph00/ph01):
//   ph00: stage (t+1).A1 -> nxt     ph01: stage (t+1).B1 -> nxt
//   ph10: stage (t+2).B0 -> cur     ph11: stage (t+2).A0 -> cur, then vmcnt(4)
// Boundary vmcnt(4): newest 4 units are (t+2).{B0,A0} -> all 4 halves of t+1 proven
// resident. Prologue: t0.{A0,A1,B0,B1}, t1.{B0,A0}, vmcnt(4) (same invariant).
//
// Swizzle (T2, rule 21 both-sides): physical 16B slot = logical ^ (row&7); stage keeps
// LDS write linear and inverse-swizzles the per-lane GLOBAL source; ds_read applies
// slot^(row&7). 16-way conflict -> 2-way (free).

__device__ __forceinline__ void stage8(const bf16* g, int K, bf16* lds, int lane) {
  const int r = lane >> 3, s = (lane & 7) ^ r;   // inverse-swizzled global slot
  gl_lds16(g + (size_t)r * K + s * 8, lds);      // lds arg wave-uniform; HW adds lane*16B
}
__device__ __forceinline__ void stage_half(const bf16* g, int K, bf16* lds, int wv, int lane) {
  stage8(g + (size_t)(wv * 16) * K,     K, lds + (wv * 16) * 64, lane);
  stage8(g + (size_t)(wv * 16 + 8) * K, K, lds + (wv * 16 + 8) * 64, lane);
}

#define GBAR asm volatile("s_barrier" ::: "memory")

template<int MODE>
__global__ __launch_bounds__(512, 2)
void gemm256(const bf16* __restrict__ A, const bf16* __restrict__ Bt,
             const float* __restrict__ bias, float* __restrict__ out,
             bf16* __restrict__ qo, bf16* __restrict__ ko, bf16* __restrict__ vo,
             int M, int N, int K)
{
  __shared__ __attribute__((aligned(16))) bf16 As[2][256 * 64];
  __shared__ __attribute__((aligned(16))) bf16 Bs[2][256 * 64];

  const int tid  = threadIdx.x;
  const int wv   = tid >> 6, lane = tid & 63;
  const int quad = lane >> 4, l16 = lane & 15;
  const int wm   = wv >> 2, wn = wv & 3;          // 2 x 4 wave grid
  const int n0   = blockIdx.x * 256, m0 = blockIdx.y * 256;
  const int NTT  = K >> 6;

  floatx4 acc[8][4] = {};

  const bf16* Abase = A  + (size_t)m0 * K;
  const bf16* Bbase = Bt + (size_t)n0 * K;

  // prologue: t0 all 4 halves, then t1.{B0,A0} (matches steady-state in-flight set)
  stage_half(Abase,                  K, As[0],            wv, lane);
  stage_half(Abase + (size_t)128*K,  K, As[0] + 128 * 64, wv, lane);
  stage_half(Bbase,                  K, Bs[0],            wv, lane);
  stage_half(Bbase + (size_t)128*K,  K, Bs[0] + 128 * 64, wv, lane);
  stage_half(Bbase + 64,             K, Bs[1],            wv, lane);
  stage_half(Abase + 64,             K, As[1],            wv, lane);
  asm volatile("s_waitcnt vmcnt(4)" ::: "memory");
  GBAR;

#define LOADA(qm)                                                          \
  _Pragma("unroll")                                                        \
  for (int mi = 0; mi < 4; mi++) {                                         \
    const int row = wm * 128 + (qm) * 64 + mi * 16 + l16;                  \
    const bf16* rp = bufA + row * 64;                                      \
    af[mi][0] = *(const bf16x8*)(rp + (( quad      ^ (row & 7)) * 8));     \
    af[mi][1] = *(const bf16x8*)(rp + (((4 | quad) ^ (row & 7)) * 8));     \
  }
#define LOADB(qn)                                                          \
  _Pragma("unroll")                                                        \
  for (int ni = 0; ni < 2; ni++) {                                         \
    const int row = wn * 64 + (qn) * 32 + ni * 16 + l16;                   \
    const bf16* rp = bufB + row * 64;                                      \
    bfr[(qn)*2+ni][0] = *(const bf16x8*)(rp + (( quad      ^ (row & 7)) * 8)); \
    bfr[(qn)*2+ni][1] = *(const bf16x8*)(rp + (((4 | quad) ^ (row & 7)) * 8)); \
  }
#define MM(qm, qn)                                                         \
  __builtin_amdgcn_s_setprio(1);                                           \
  _Pragma("unroll")                                                        \
  for (int mi = 0; mi < 4; mi++)                                           \
    _Pragma("unroll")                                                      \
    for (int ni = 0; ni < 2; ni++) {                                       \
      acc[(qm)*4+mi][(qn)*2+ni] = __builtin_amdgcn_mfma_f32_16x16x32_bf16( \
          af[mi][0], bfr[(qn)*2+ni][0], acc[(qm)*4+mi][(qn)*2+ni], 0, 0, 0); \
      acc[(qm)*4+mi][(qn)*2+ni] = __builtin_amdgcn_mfma_f32_16x16x32_bf16( \
          af[mi][1], bfr[(qn)*2+ni][1], acc[(qm)*4+mi][(qn)*2+ni], 0, 0, 0); \
    }                                                                      \
  __builtin_amdgcn_s_setprio(0);

  #pragma unroll 1
  for (int t = 0; t < NTT; t++) {
    const int cur = t & 1;
    const bf16* bufA = As[cur];
    const bf16* bufB = Bs[cur];
    bf16* nA = As[cur ^ 1];   // tile t+1 buffer
    bf16* nB = Bs[cur ^ 1];
    bf16* cA = As[cur];       // tile t+2 buffer (this one, freed as we go)
    bf16* cB = Bs[cur];
    const int kn1 = (t + 1) * 64, kn2 = (t + 2) * 64;
    const bool h1 = (t + 1 < NTT), h2 = (t + 2 < NTT);

    bf16x8 af[4][2], bfr[4][2];

    // ---- ph00: read A-q0 (8) + B-q0 (4); stage (t+1).A1 -> nxt ----
    LOADA(0);
    LOADB(0);
    if (h1) stage_half(Abase + (size_t)128 * K + kn1, K, nA + 128 * 64, wv, lane);
    GBAR;
    MM(0, 0);
    GBAR;

    // ---- ph01: read B-q1 (4); stage (t+1).B1 -> nxt ----
    LOADB(1);
    if (h1) stage_half(Bbase + (size_t)128 * K + kn1, K, nB + 128 * 64, wv, lane);
    GBAR;
    MM(0, 1);
    GBAR;

    // ---- ph10: read A-q1 (8); stage (t+2).B0 -> cur (all B reads retired) ----
    LOADA(1);
    if (h2) stage_half(Bbase + kn2, K, cB, wv, lane);
    GBAR;
    MM(1, 0);
    GBAR;

    // ---- ph11: no reads; stage (t+2).A0 -> cur (all A reads retired); vmcnt ----
    if (h2) stage_half(Abase + kn2, K, cA, wv, lane);
    GBAR;
    MM(1, 1);
    asm volatile("s_waitcnt vmcnt(4)" ::: "memory");
    GBAR;
  }

#undef LOADA
#undef LOADB
#undef MM

  // epilogue
  #pragma unroll
  for (int mi8 = 0; mi8 < 8; mi8++) {
    #pragma unroll
    for (int nf = 0; nf < 4; nf++) {
      const int col = n0 + wn * 64 + nf * 16 + l16;
      const float bv = bias[col];
      #pragma unroll
      for (int r = 0; r < 4; r++) {
        const int row = m0 + wm * 128 + mi8 * 16 + quad * 4 + r;
        const float val = acc[mi8][nf][r] + bv;
        if (MODE == 0) {
          const int b = row >> 11, tt = row & 2047;
          const int s = col >> 10, c = col & 1023;
          const int h = c >> 6, d = c & 63;
          bf16* dst = (s == 0) ? qo : (s == 1) ? ko : vo;
          dst[((size_t)(b * H_ + h) * T_ + tt) * D_ + d] = (bf16)val;
        } else {
          out[(size_t)row * N + col] = val;
        }
      }
    }
  }
}

// ---------------- flash attention (unchanged this round) ----------------
__global__ __launch_bounds__(256)
void attn_kernel(const bf16* __restrict__ Q, const bf16* __restrict__ Kp,
                 const bf16* __restrict__ Vtp, bf16* __restrict__ Y)
{
  __shared__ __attribute__((aligned(16))) bf16 Ks[2][64 * 72];  // [key][d]
  __shared__ __attribute__((aligned(16))) bf16 Vs[2][64 * 72];  // [d][slot]
  __shared__ __attribute__((aligned(16))) bf16 Ps[4][16 * 72];  // per-wave [row][slot]

  const int tid  = threadIdx.x;
  const int w    = tid >> 6, lane = tid & 63;
  const int quad = lane >> 4, l16 = lane & 15;
  const int bh = blockIdx.x;
  const int b = bh >> 4, h = bh & 15;
  const int pr = blockIdx.y;        // pair index 0..7

  const int sk = tid >> 2;          // staging row (key for K, d for V)
  const int sc = (tid & 3) * 16;    // staging 32B segment

  const float SC = 0.125f * 1.44269504088896f;  // 1/sqrt(D) * log2(e)

  #pragma unroll 1
  for (int sel = 0; sel < 2; sel++) {
    const int qt = sel ? pr : 15 - pr;   // heavy tile first
    const int q0 = qt * 128;
    const int nch = 2 * qt + 2;

    bf16x8 qf[2][2];
    #pragma unroll
    for (int mt = 0; mt < 2; mt++) {
      const bf16* qp = Q + ((size_t)bh * T_ + q0 + mt * 64 + w * 16 + l16) * D_ + quad * 8;
      qf[mt][0] = *(const bf16x8*)qp;
      qf[mt][1] = *(const bf16x8*)(qp + 32);
    }

    floatx4 o[2][4] = {};
    float l_r[2][4] = {};

    const bf16* kpp = Kp  + (size_t)bh * T_ * D_ + (size_t)sk * D_ + sc;
    const bf16* vpp = Vtp + (size_t)bh * D_ * T_ + (size_t)sk * T_ + sc;

    {
      const bf16x8 k0 = *(const bf16x8*)kpp, k1 = *(const bf16x8*)(kpp + 8);
      const bf16x8 v0 = *(const bf16x8*)vpp, v1 = *(const bf16x8*)(vpp + 8);
      bf16* kd = Ks[0] + sk * 72 + sc;
      *(bf16x8*)kd = k0; *(bf16x8*)(kd + 8) = k1;
      bf16* vd = Vs[0] + sk * 72 + sc;
      *(bf16x8*)vd = v0; *(bf16x8*)(vd + 8) = v1;
      kpp += 64 * D_; vpp += 64;
    }
    __syncthreads();

    #pragma unroll 1
    for (int c = 0; c < nch; c++) {
      const int cur = c & 1;

      bf16x8 nk0, nk1, nv0, nv1;
      const bool have = (c + 1 < nch);
      if (have) {
        nk0 = *(const bf16x8*)kpp; nk1 = *(const bf16x8*)(kpp + 8);
        nv0 = *(const bf16x8*)vpp; nv1 = *(const bf16x8*)(vpp + 8);
        kpp += 64 * D_; vpp += 64;
      }

      const bf16* KsC = Ks[cur];
      const bf16* VsC = Vs[cur];
      const int kv0 = c * 64;
      const bool act0 = (c < nch - 1);  // mt0 fully masked on last chunk

      floatx4 s[2][4];
      #pragma unroll
      for (int nt = 0; nt < 4; nt++) {
        const bf16x8 kf0 = *(const bf16x8*)(KsC + (nt * 16 + l16) * 72 + quad * 8);
        const bf16x8 kf1 = *(const bf16x8*)(KsC + (nt * 16 + l16) * 72 + 32 + quad * 8);
        if (act0) {
          floatx4 z = {};
          z = __builtin_amdgcn_mfma_f32_16x16x32_bf16(qf[0][0], kf0, z, 0, 0, 0);
          s[0][nt] = __builtin_amdgcn_mfma_f32_16x16x32_bf16(qf[0][1], kf1, z, 0, 0, 0);
        }
        floatx4 z = {};
        z = __builtin_amdgcn_mfma_f32_16x16x32_bf16(qf[1][0], kf0, z, 0, 0, 0);
        s[1][nt] = __builtin_amdgcn_mfma_f32_16x16x32_bf16(qf[1][1], kf1, z, 0, 0, 0);
      }

      bf16x8 vfr[4][2];
      #pragma unroll
      for (int nt = 0; nt < 4; nt++) {
        vfr[nt][0] = *(const bf16x8*)(VsC + (nt * 16 + l16) * 72 + quad * 8);
        vfr[nt][1] = *(const bf16x8*)(VsC + (nt * 16 + l16) * 72 + 32 + quad * 8);
      }

      #pragma unroll
      for (int mt = 0; mt < 2; mt++) {
        if (mt == 0 && !act0) continue;
        const bool diag = (c == 2 * qt + mt);
        #pragma unroll
        for (int r = 0; r < 4; r++) {
          const int qrow = q0 + mt * 64 + w * 16 + quad * 4 + r;
          float x0 = s[mt][0][r], x1 = s[mt][1][r], x2 = s[mt][2][r], x3 = s[mt][3][r];
          if (diag) {
            if (kv0      + l16 > qrow) x0 = -1e30f;
            if (kv0 + 16 + l16 > qrow) x1 = -1e30f;
            if (kv0 + 32 + l16 > qrow) x2 = -1e30f;
            if (kv0 + 48 + l16 > qrow) x3 = -1e30f;
          }
          const float e0 = __builtin_amdgcn_exp2f(fmaf(x0, SC, -8.f));
          const float e1 = __builtin_amdgcn_exp2f(fmaf(x1, SC, -8.f));
          const float e2 = __builtin_amdgcn_exp2f(fmaf(x2, SC, -8.f));
          const float e3 = __builtin_amdgcn_exp2f(fmaf(x3, SC, -8.f));
          l_r[mt][r] += (e0 + e1) + (e2 + e3);
          uint2 pk;
          pk.x = pack_bf16_trunc(e0, e1);
          pk.y = pack_bf16_trunc(e2, e3);
          *(uint2*)(&Ps[w][(quad * 4 + r) * 72 + l16 * 4]) = pk;
        }
        const bf16x8 pf0 = *(const bf16x8*)(&Ps[w][l16 * 72 + quad * 8]);
        const bf16x8 pf1 = *(const bf16x8*)(&Ps[w][l16 * 72 + 32 + quad * 8]);
        #pragma unroll
        for (int nt = 0; nt < 4; nt++) {
          o[mt][nt] = __builtin_amdgcn_mfma_f32_16x16x32_bf16(pf0, vfr[nt][0], o[mt][nt], 0, 0, 0);
          o[mt][nt] = __builtin_amdgcn_mfma_f32_16x16x32_bf16(pf1, vfr[nt][1], o[mt][nt], 0, 0, 0);
        }
      }

      if (have) {
        bf16* kd = Ks[cur ^ 1] + sk * 72 + sc;
        *(bf16x8*)kd = nk0; *(bf16x8*)(kd + 8) = nk1;
        bf16* vd = Vs[cur ^ 1] + sk * 72 + sc;
        *(bf16x8*)vd = nv0; *(bf16x8*)(vd + 8) = nv1;
      }
      __syncthreads();
    }

    #pragma unroll
    for (int mt = 0; mt < 2; mt++) {
      #pragma unroll
      for (int r = 0; r < 4; r++) {
        float ls = l_r[mt][r];
        ls += __shfl_xor(ls, 1);
        ls += __shfl_xor(ls, 2);
        ls += __shfl_xor(ls, 4);
        ls += __shfl_xor(ls, 8);
        const float inv = 1.f / ls;
        const int t = q0 + mt * 64 + w * 16 + quad * 4 + r;
        #pragma unroll
        for (int nt = 0; nt < 4; nt++)
          Y[((size_t)b * T_ + t) * C_ + h * D_ + nt * 16 + l16] = (bf16)(o[mt][nt][r] * inv);
      }
    }
  }
}

extern "C" void kernel_launch(void* const* d_in, const int* in_sizes, int n_in,
                              void* d_out, int out_size, void* d_ws, size_t ws_size,
                              hipStream_t stream)
{
  const float* x      = (const float*)d_in[0];
  const float* W_attn = (const float*)d_in[1];
  const float* b_attn = (const float*)d_in[2];
  const float* W_proj = (const float*)d_in[3];
  const float* b_proj = (const float*)d_in[4];
  float* out = (float*)d_out;

  bf16* xb  = (bf16*)d_ws;                  // [8192,1024]; reused as Vtp after gemm<0>
  bf16* wat = xb  + (size_t)M_ * C_;
  bf16* wpt = wat + (size_t)N3 * C_;
  bf16* qb  = wpt + (size_t)C_ * C_;
  bf16* kb  = qb  + (size_t)M_ * C_;
  bf16* vb  = kb  + (size_t)M_ * C_;
  bf16* yb  = vb  + (size_t)M_ * C_;
  bf16* vtb = xb;                           // [B,H,D,T] permuted

  cast_to_bf16<<<dim3(M_ * C_ / 1024), 256, 0, stream>>>(x, xb, M_ * C_);
  transpose_cast<<<dim3(N3 / 32, C_ / 32), 256, 0, stream>>>(W_attn, wat, C_, N3);
  transpose_cast<<<dim3(C_ / 32, C_ / 32), 256, 0, stream>>>(W_proj, wpt, C_, C_);
  gemm256<0><<<dim3(N3 / 256, M_ / 256), 512, 0, stream>>>(
      xb, wat, b_attn, nullptr, qb, kb, vb, M_, N3, C_);
  transpose_v<<<dim3(T_ / 64, 1, B_ * H_), 256, 0, stream>>>(vb, vtb);
  attn_kernel<<<dim3(B_ * H_, 8), 256, 0, stream>>>(qb, kb, vtb, yb);
  gemm_bt<1><<<dim3(C_ / 128, M_ / 128), 256, 0, stream>>>(
      yb, wpt, b_proj, out, nullptr, nullptr, nullptr, M_, C_, C_);
}